// Round 6
// baseline (490.393 us; speedup 1.0000x reference)
//
#include <hip/hip_runtime.h>
#include <math.h>

// OctreeAttention: C=256, H=8, HD=32, K=32, G=8, W=40 (pad 48), NW=4096, RPE rows=153
#define SCALE_F 0.17677669529663687f  // 32^-0.5

typedef __bf16 bf16x8 __attribute__((ext_vector_type(8)));
typedef float f32x4 __attribute__((ext_vector_type(4)));

__device__ __forceinline__ unsigned short f2bf(float f) {
  unsigned u = __builtin_bit_cast(unsigned, f);
  u = (u + 0x7FFFu + ((u >> 16) & 1u)) >> 16;
  return (unsigned short)u;
}
__device__ __forceinline__ float bf2f(unsigned short u) {
  return __builtin_bit_cast(float, (unsigned)u << 16);
}
__device__ __forceinline__ unsigned pk2(float a, float b) {
  return (unsigned)f2bf(a) | ((unsigned)f2bf(b) << 16);
}
__device__ __forceinline__ bf16x8 ld16(const void* p) {
  int4 v = *(const int4*)p;
  return __builtin_bit_cast(bf16x8, v);
}
__device__ __forceinline__ bf16x8 cvt8(float4 x, float4 y) {
  int4 v;
  v.x = (int)pk2(x.x, x.y); v.y = (int)pk2(x.z, x.w);
  v.z = (int)pk2(y.x, y.y); v.w = (int)pk2(y.z, y.w);
  return __builtin_bit_cast(bf16x8, v);
}
__device__ __forceinline__ void gll16(const void* g, void* l) {
  __builtin_amdgcn_global_load_lds(
      (const __attribute__((address_space(1))) unsigned int*)g,
      (__attribute__((address_space(3))) unsigned int*)l, 16, 0, 0);
}

// =======================================================================
// NEW PATH: 4-kernel split (needs ws_size >= 84.5 MB)
// =======================================================================

// ---- prep: weights -> bf16, transposed, PRE-SWIZZLED for frag-ready LDS ----
// layout: chunk (nh,kc) of wTq is 24576 B = [384 n][64 B], byte (n*64+cb) holds
// wT[n][kc*32 + ((cb ^ s(n))>>1)], s(n)=((n>>1)&3)<<4.  pTq: 8 chunks 16384 B.
__global__ void octa_prep2(const float* __restrict__ qkv_w, const float* __restrict__ proj_w,
                           unsigned short* __restrict__ wTq, unsigned short* __restrict__ pTq)
{
  int e = blockIdx.x * 256 + threadIdx.x;   // 262144
  if (e < 196608) {
    int nh = e / 98304, rr = e % 98304;
    int kc = rr / 12288, p2 = rr % 12288;
    int n = p2 >> 5, cw = p2 & 31;
    int kl = cw ^ (((n >> 1) & 3) << 3);
    wTq[e] = f2bf(qkv_w[(size_t)(kc * 32 + kl) * 768 + nh * 384 + n]);
  } else {
    int e2 = e - 196608;
    int kc = e2 >> 13, p2 = e2 & 8191;
    int n = p2 >> 5, cw = p2 & 31;
    int kl = cw ^ (((n >> 1) & 3) << 3);
    pTq[e2] = f2bf(proj_w[(size_t)(kc * 32 + kl) * 256 + n]);
  }
}

// ---- kernel 1: qkv GEMM (M=163840, N=384/block, K=256) ----
// grid 5120 (bm = bid>>1, nh = bid&1), 512 thr, 8 waves (2M x 4N).
// A register-streamed (2 rows/lane, depth-2 prefetch), B gll16-dbuf.
// Counted vmcnt(4) + raw s_barrier: A loads stay in flight across barriers.
#define K2_B0 0
#define K2_B1 24576
#define K2_LDS 49152

__global__ __launch_bounds__(512, 4)
void octa_qkv(const float* __restrict__ data, const float* __restrict__ qkv_b,
              const unsigned short* __restrict__ wTq, float* __restrict__ ws,
              char* __restrict__ qg, char* __restrict__ kg, char* __restrict__ vg)
{
  extern __shared__ char smem[];
  const int tid = threadIdx.x, lane = tid & 63, wid = tid >> 6;
  const int ql = lane & 15, lg = lane >> 4;
  const int bm = blockIdx.x >> 1, nh = blockIdx.x & 1;
  const int wr = wid >> 2, wc = wid & 3;

  // per-lane A rows: r0 = bm*64 + wr*32 + ql, r1 = r0 + 16; cols t*32 + lg*8 ..
  const float* a0 = data + ((size_t)bm * 64 + wr * 32 + ql) * 256 + lg * 8;
  const float* a1 = a0 + 16 * 256;
  const char* wbase = (const char*)wTq + (size_t)nh * 196608;

  // prologue, issue order pinned: B(0) x3, A(0) x4, A(1) x4  -> 11 in flight
  #pragma unroll
  for (int it = 0; it < 3; ++it)
    gll16(wbase + wid * 3072 + it * 1024 + lane * 16,
          smem + K2_B0 + wid * 3072 + it * 1024);
  __builtin_amdgcn_sched_barrier(0);
  float4 Ab[2][4];
  Ab[0][0] = *(const float4*)(a0);
  Ab[0][1] = *(const float4*)(a0 + 4);
  Ab[0][2] = *(const float4*)(a1);
  Ab[0][3] = *(const float4*)(a1 + 4);
  __builtin_amdgcn_sched_barrier(0);
  Ab[1][0] = *(const float4*)(a0 + 32);
  Ab[1][1] = *(const float4*)(a0 + 36);
  Ab[1][2] = *(const float4*)(a1 + 32);
  Ab[1][3] = *(const float4*)(a1 + 36);
  __builtin_amdgcn_sched_barrier(0);

  f32x4 acc[2][6];
  #pragma unroll
  for (int m = 0; m < 2; ++m)
    #pragma unroll
    for (int n = 0; n < 6; ++n) acc[m][n] = (f32x4){0.f, 0.f, 0.f, 0.f};

  #pragma unroll
  for (int t = 0; t < 8; ++t) {
    // wait: drain B(t)+A(t) (oldest 7), keep A(t+1) (newest 4) in flight
    if (t < 7) asm volatile("s_waitcnt vmcnt(4)" ::: "memory");
    else       asm volatile("s_waitcnt vmcnt(0)" ::: "memory");
    __builtin_amdgcn_s_barrier();
    __builtin_amdgcn_sched_barrier(0);   // no ds_read hoisted above the barrier

    // compute chunk t
    bf16x8 af0 = cvt8(Ab[t & 1][0], Ab[t & 1][1]);
    bf16x8 af1 = cvt8(Ab[t & 1][2], Ab[t & 1][3]);
    const char* bb = smem + ((t & 1) ? K2_B1 : K2_B0);
    #pragma unroll
    for (int nt = 0; nt < 6; ++nt) {
      int n = wc * 96 + nt * 16 + ql;
      bf16x8 bf = ld16(bb + n * 64 + ((lg * 16) ^ (((n >> 1) & 3) << 4)));
      acc[0][nt] = __builtin_amdgcn_mfma_f32_16x16x32_bf16(af0, bf, acc[0][nt], 0, 0, 0);
      acc[1][nt] = __builtin_amdgcn_mfma_f32_16x16x32_bf16(af1, bf, acc[1][nt], 0, 0, 0);
    }
    __builtin_amdgcn_sched_barrier(0);

    // issue B(t+1) then A(t+2)  (this exact order; counted by the vmcnt above)
    if (t < 7) {
      char* bb1 = smem + (((t + 1) & 1) ? K2_B1 : K2_B0);
      #pragma unroll
      for (int it = 0; it < 3; ++it)
        gll16(wbase + (size_t)(t + 1) * 24576 + wid * 3072 + it * 1024 + lane * 16,
              bb1 + wid * 3072 + it * 1024);
    }
    __builtin_amdgcn_sched_barrier(0);
    if (t < 6) {
      Ab[t & 1][0] = *(const float4*)(a0 + (t + 2) * 32);
      Ab[t & 1][1] = *(const float4*)(a0 + (t + 2) * 32 + 4);
      Ab[t & 1][2] = *(const float4*)(a1 + (t + 2) * 32);
      Ab[t & 1][3] = *(const float4*)(a1 + (t + 2) * 32 + 4);
    }
    __builtin_amdgcn_sched_barrier(0);
  }

  // epilogue: bias + std partials + scatter to q/k/vT bf16 layouts
  #pragma unroll
  for (int nt = 0; nt < 6; ++nt) {
    int colg = nh * 384 + wc * 96 + nt * 16 + ql;
    int tensor = colg >> 8, h = (colg >> 5) & 7, d = colg & 31;
    float bias = qkv_b[colg];
    float s1 = 0.f, s2 = 0.f;
    #pragma unroll
    for (int mt = 0; mt < 2; ++mt) {
      float v4[4];
      #pragma unroll
      for (int r = 0; r < 4; ++r) {
        float v = acc[mt][nt][r] + bias;
        s1 += v; s2 += v * v;
        v4[r] = v;
      }
      int tg0 = bm * 64 + wr * 32 + mt * 16 + lg * 4;   // 4-aligned, never crosses window
      int w = tg0 / 40, tk0 = tg0 - w * 40;
      size_t slice = (size_t)(w * 8 + h) * 2560;
      if (tensor == 0) {
        #pragma unroll
        for (int r = 0; r < 4; ++r)
          *(unsigned short*)(qg + slice + (tk0 + r) * 64 + d * 2) = f2bf(v4[r] * SCALE_F);
      } else if (tensor == 1) {
        #pragma unroll
        for (int r = 0; r < 4; ++r)
          *(unsigned short*)(kg + slice + (tk0 + r) * 64 + d * 2) = f2bf(v4[r]);
      } else {
        *(uint2*)(vg + slice + d * 80 + tk0 * 2) =
            make_uint2(pk2(v4[0], v4[1]), pk2(v4[2], v4[3]));
      }
    }
    s1 += __shfl_xor(s1, 16); s1 += __shfl_xor(s1, 32);
    s2 += __shfl_xor(s2, 16); s2 += __shfl_xor(s2, 32);
    if (lg == 0) { atomicAdd(ws + colg, s1); atomicAdd(ws + 768 + colg, s2); }
  }
}

// ---- kernel 2: attention, 1 window/block, 8 head-waves, q/k/v direct-from-global ----
#define A2_MSK 0       // mask^T bf16 [40 kj][104 B rows]
#define A2_IDX 4160    // packed idx [32 kj][128 B], XOR bit6 by kj&1
#define A2_RPT 8256    // rpeT f32 [8 h][160]
#define A2_P   13376   // per-wave P [48][80 B] x8 = 30720
#define A2_LDS 44096

__global__ __launch_bounds__(512, 4)
void octa_attn(const char* __restrict__ qg, const char* __restrict__ kg,
               const char* __restrict__ vg, const float* __restrict__ maskp,
               const int* __restrict__ rel_pos, const float* __restrict__ rpe_table,
               char* __restrict__ Og)
{
  extern __shared__ char smem[];
  const int tid = threadIdx.x, w = blockIdx.x, wid = tid >> 6;
  const int lane = tid & 63, ql = lane & 15, lg = lane >> 4, h = wid;
  const int perm = ql * 64 + lg * 16;
  const int vperm = ql * 80 + lg * 16;
  const char* qb = qg + (size_t)(w * 8 + h) * 2560;
  const char* kb = kg + (size_t)(w * 8 + h) * 2560;
  const char* vb = vg + (size_t)(w * 8 + h) * 2560;

  // issue all fragment loads up-front (latency hides under phase-0 staging)
  bf16x8 kf0 = ld16(kb + perm), kf1 = ld16(kb + 1024 + perm), kf2 = ld16(kb + 2048 + perm);
  bf16x8 qf0 = ld16(qb + perm), qf1 = ld16(qb + 1024 + perm), qf2 = ld16(qb + 2048 + perm);
  bf16x8 vA = ld16(vb + vperm);              // d 0..15,  kj 0..31
  bf16x8 vB = ld16(vb + 1280 + vperm);       // d 16..31, kj 0..31
  bf16x8 vC = ld16(vb + 64 + vperm);         // d 0..15,  kj 32..39 (lg=0 only valid)
  bf16x8 vD = ld16(vb + 1280 + 64 + vperm);  // d 16..31, kj 32..39
  if (lg != 0) {      // kj 40..63 don't exist in global: zero them (NaN-safe)
    int4 z = {0, 0, 0, 0};
    vC = __builtin_bit_cast(bf16x8, z);
    vD = __builtin_bit_cast(bf16x8, z);
  }

  // phase 0: stage mask^T, packed idx, transposed rpe
  for (int f = tid; f < 1600; f += 512) {
    float m = maskp[(size_t)w * 1600 + f];
    int qi = f / 40, kj = f - qi * 40;
    *(unsigned short*)(smem + A2_MSK + kj * 104 + qi * 2) = f2bf(m);
  }
  for (int f = tid; f < 1024; f += 512) {
    const int* rp = rel_pos + ((size_t)w * 1024 + f) * 3;
    int c0 = rp[0], c1 = rp[1], c2 = rp[2];
    c0 = min(25, max(-25, c0)); c1 = min(25, max(-25, c1)); c2 = min(25, max(-25, c2));
    unsigned pk = (unsigned)(c0 + 25) | ((unsigned)(c1 + 76) << 10) | ((unsigned)(c2 + 127) << 20);
    int qi8 = f >> 5, kj8 = f & 31;
    *(unsigned*)(smem + A2_IDX + kj8 * 128 + ((qi8 * 4) ^ ((kj8 & 1) << 6))) = pk;
  }
  for (int f = tid; f < 1224; f += 512)
    *(float*)(smem + A2_RPT + (((f & 7) * 160 + (f >> 3)) << 2)) = rpe_table[f];
  __syncthreads();

  // QK^T: ST[kj][qi] = mfma(A=k, B=q)
  f32x4 st[9];
  {
    bf16x8 kf[3] = {kf0, kf1, kf2}, qf[3] = {qf0, qf1, qf2};
    #pragma unroll
    for (int a = 0; a < 3; ++a)
      #pragma unroll
      for (int b = 0; b < 3; ++b)
        st[a * 3 + b] = __builtin_amdgcn_mfma_f32_16x16x32_bf16(
            kf[a], qf[b], (f32x4){0.f, 0.f, 0.f, 0.f}, 0, 0, 0);
  }

  // logits + mask + rpe; per-column (qi) max
  float mx[3] = {-3e38f, -3e38f, -3e38f};
  #pragma unroll
  for (int a = 0; a < 3; ++a) {
    #pragma unroll
    for (int b = 0; b < 3; ++b) {
      #pragma unroll
      for (int r = 0; r < 4; ++r) {
        int kj = a * 16 + lg * 4 + r;
        int qi = b * 16 + ql;
        float s = st[a * 3 + b][r];
        if (kj < 40) {
          if (qi < 40) {
            s += bf2f(*(const unsigned short*)(smem + A2_MSK + kj * 104 + qi * 2));
            if (kj >= 8 && qi >= 8) {
              unsigned pk = *(const unsigned*)(smem + A2_IDX + (kj - 8) * 128 +
                                               (((qi - 8) * 4) ^ (((kj - 8) & 1) << 6)));
              s += *(const float*)(smem + A2_RPT + ((h * 160 + (pk & 1023)) << 2))
                 + *(const float*)(smem + A2_RPT + ((h * 160 + ((pk >> 10) & 1023)) << 2))
                 + *(const float*)(smem + A2_RPT + ((h * 160 + (pk >> 20)) << 2));
            }
          }
        } else {
          s = -1e30f;
        }
        st[a * 3 + b][r] = s;
        mx[b] = fmaxf(mx[b], s);
      }
    }
  }
  #pragma unroll
  for (int b = 0; b < 3; ++b) {
    mx[b] = fmaxf(mx[b], __shfl_xor(mx[b], 16));
    mx[b] = fmaxf(mx[b], __shfl_xor(mx[b], 32));
  }
  float sum[3] = {0.f, 0.f, 0.f};
  #pragma unroll
  for (int a = 0; a < 3; ++a)
    #pragma unroll
    for (int b = 0; b < 3; ++b)
      #pragma unroll
      for (int r = 0; r < 4; ++r) {
        float e = __expf(st[a * 3 + b][r] - mx[b]);
        st[a * 3 + b][r] = e;
        sum[b] += e;
      }
  float inv[3];
  #pragma unroll
  for (int b = 0; b < 3; ++b) {
    sum[b] += __shfl_xor(sum[b], 16);
    sum[b] += __shfl_xor(sum[b], 32);
    inv[b] = 1.f / sum[b];
  }

  // PV in two kj-halves; per-wave P buffer
  char* pb_ = smem + A2_P + wid * 3840;
  f32x4 ot[6];
  #pragma unroll
  for (int i = 0; i < 6; ++i) ot[i] = (f32x4){0.f, 0.f, 0.f, 0.f};

  #pragma unroll
  for (int a = 0; a < 2; ++a)
    #pragma unroll
    for (int b = 0; b < 3; ++b)
      #pragma unroll
      for (int r = 0; r < 4; ++r) {
        int kj = a * 16 + lg * 4 + r, qi = b * 16 + ql;
        *(unsigned short*)(pb_ + qi * 80 + kj * 2) = f2bf(st[a * 3 + b][r] * inv[b]);
      }
  asm volatile("" ::: "memory");
  #pragma unroll
  for (int b = 0; b < 3; ++b) {
    bf16x8 pf = ld16(pb_ + (b * 16 + ql) * 80 + lg * 16);
    ot[b]     = __builtin_amdgcn_mfma_f32_16x16x32_bf16(vA, pf, ot[b], 0, 0, 0);
    ot[3 + b] = __builtin_amdgcn_mfma_f32_16x16x32_bf16(vB, pf, ot[3 + b], 0, 0, 0);
  }
  asm volatile("" ::: "memory");
  #pragma unroll
  for (int b = 0; b < 3; ++b) {
    int qi = b * 16 + ql;
    #pragma unroll
    for (int r = 0; r < 4; ++r)
      *(unsigned short*)(pb_ + qi * 80 + (lg * 4 + r) * 2) = f2bf(st[6 + b][r] * inv[b]);
    *(uint2*)(pb_ + qi * 80 + 32 + lg * 8) = make_uint2(0u, 0u);
  }
  asm volatile("" ::: "memory");
  #pragma unroll
  for (int b = 0; b < 3; ++b) {
    bf16x8 pf = ld16(pb_ + (b * 16 + ql) * 80 + lg * 16);
    ot[b]     = __builtin_amdgcn_mfma_f32_16x16x32_bf16(vC, pf, ot[b], 0, 0, 0);
    ot[3 + b] = __builtin_amdgcn_mfma_f32_16x16x32_bf16(vD, pf, ot[3 + b], 0, 0, 0);
  }

  // O store (Og aliases kg: wait for ALL waves' k reads to be consumed)
  __syncthreads();
  #pragma unroll
  for (int dm = 0; dm < 2; ++dm)
    #pragma unroll
    for (int b = 0; b < 3; ++b) {
      int qi = b * 16 + ql;
      if (b == 2 && ql >= 8) continue;   // tokens >= 40 don't exist
      unsigned u0 = pk2(ot[dm * 3 + b][0], ot[dm * 3 + b][1]);
      unsigned u1 = pk2(ot[dm * 3 + b][2], ot[dm * 3 + b][3]);
      int tg = w * 40 + qi;
      int colb = (h * 32 + dm * 16 + lg * 4) * 2;
      *(uint2*)(Og + (size_t)tg * 512 + (colb ^ (((tg >> 1) & 3) << 4))) = make_uint2(u0, u1);
    }
}

// ---- kernel 3: proj GEMM (M=163840, N=256, K=256), all-gll16 dbuf ----
#define P3_A0 0
#define P3_A1 8192
#define P3_B0 16384
#define P3_B1 32768
#define P3_LDS 49152

__global__ __launch_bounds__(512, 4)
void octa_proj(const char* __restrict__ Og, const unsigned short* __restrict__ pTq,
               const float* __restrict__ proj_b, float* __restrict__ out)
{
  extern __shared__ char smem[];
  const int tid = threadIdx.x, lane = tid & 63, wid = tid >> 6;
  const int ql = lane & 15, lg = lane >> 4;
  const int bm = blockIdx.x;
  const int wr = wid >> 2, wc = wid & 3;
  const char* pbase = (const char*)pTq;

  // prologue: stage A0 (1 slot/thread) + B0 (2/thread)
  gll16(Og + ((size_t)bm * 128 + (tid >> 2)) * 512 + (tid & 3) * 16,
        smem + P3_A0 + wid * 1024);
  #pragma unroll
  for (int it = 0; it < 2; ++it)
    gll16(pbase + (wid * 128 + it * 64 + lane) * 16, smem + P3_B0 + wid * 2048 + it * 1024);
  __syncthreads();

  f32x4 acc[4][4];
  #pragma unroll
  for (int m = 0; m < 4; ++m)
    #pragma unroll
    for (int n = 0; n < 4; ++n) acc[m][n] = (f32x4){0.f, 0.f, 0.f, 0.f};

  #pragma unroll
  for (int t = 0; t < 8; ++t) {
    if (t < 7) {
      char* ab1 = smem + (((t + 1) & 1) ? P3_A1 : P3_A0);
      char* bb1 = smem + (((t + 1) & 1) ? P3_B1 : P3_B0);
      gll16(Og + ((size_t)bm * 128 + (tid >> 2)) * 512 + (t + 1) * 64 + (tid & 3) * 16,
            ab1 + wid * 1024);
      #pragma unroll
      for (int it = 0; it < 2; ++it)
        gll16(pbase + (size_t)(t + 1) * 16384 + (wid * 128 + it * 64 + lane) * 16,
              bb1 + wid * 2048 + it * 1024);
    }
    const char* ab = smem + ((t & 1) ? P3_A1 : P3_A0);
    const char* bb = smem + ((t & 1) ? P3_B1 : P3_B0);
    bf16x8 af[4];
    #pragma unroll
    for (int mt = 0; mt < 4; ++mt) {
      int row = wr * 64 + mt * 16 + ql;
      af[mt] = ld16(ab + row * 64 + ((lg * 16) ^ (((row >> 1) & 3) << 4)));
    }
    #pragma unroll
    for (int nt = 0; nt < 4; ++nt) {
      int n = wc * 64 + nt * 16 + ql;
      bf16x8 bf = ld16(bb + n * 64 + ((lg * 16) ^ (((n >> 1) & 3) << 4)));
      #pragma unroll
      for (int mt = 0; mt < 4; ++mt)
        acc[mt][nt] = __builtin_amdgcn_mfma_f32_16x16x32_bf16(af[mt], bf, acc[mt][nt], 0, 0, 0);
    }
    __syncthreads();
  }

  #pragma unroll
  for (int nt = 0; nt < 4; ++nt) {
    int col = wc * 64 + nt * 16 + ql;
    float pb = proj_b[col];
    #pragma unroll
    for (int mt = 0; mt < 4; ++mt)
      #pragma unroll
      for (int r = 0; r < 4; ++r) {
        int tg = bm * 128 + wr * 64 + mt * 16 + lg * 4 + r;
        out[(size_t)tg * 256 + col] = acc[mt][nt][r] + pb;
      }
  }
}

// ---- std finalize (shared by both paths) ----
__global__ void octa_std(const float* __restrict__ ws, float* __restrict__ out,
                         int total_rows, size_t off)
{
  int j = blockIdx.x * 256 + threadIdx.x;
  if (j < 768) {
    float s = ws[j], ss = ws[768 + j];
    float T = (float)total_rows;
    float var = (ss - s * s / T) / (T - 1.f);
    out[off + j] = sqrtf(fmaxf(var, 0.f));
  }
}

// =======================================================================
// FALLBACK PATH: round-4 fused kernel (verified), used if ws too small
// =======================================================================
#define O_RPE 0
#define O_MSK 4896
#define O_IDX 8096
#define O_A   12192
#define O_ATT 36768
#define B1_SZ 49152
#define ATT_STRIDE 11776
#define AK 3840
#define AV 7680
#define B2_S (O_ATT + 94208)
#define B2_A O_ATT
#define LDS_BYTES_V4 163744

__device__ __forceinline__ int a_addr(int row, int byte) {
  return O_A + row * 512 + (byte ^ ((row & 7) << 4));
}
__device__ __forceinline__ int v_addr(int d, int byte) {
  return AV + d * 128 + (byte ^ ((d & 7) << 4));
}

__global__ void octa_prep_v4(const float* __restrict__ qkv_w, const float* __restrict__ proj_w,
                             unsigned short* __restrict__ wTq, unsigned short* __restrict__ pTq)
{
  int idx = blockIdx.x * 256 + threadIdx.x;
  if (idx < 196608) {
    int n = idx >> 8, k = idx & 255;
    wTq[idx] = f2bf(qkv_w[k * 768 + n]);
  } else {
    int i = idx - 196608;
    int n = i >> 8, k = i & 255;
    pTq[i] = f2bf(proj_w[k * 256 + n]);
  }
}

__global__ __launch_bounds__(512, 2)
void octa_main_v4(const float* __restrict__ data, const int* __restrict__ rel_pos,
                  const float* __restrict__ maskp, const float* __restrict__ qkv_b,
                  const float* __restrict__ proj_b, const float* __restrict__ rpe_table,
                  const unsigned short* __restrict__ wTq, const unsigned short* __restrict__ pTq,
                  float* __restrict__ ws, float* __restrict__ out)
{
  extern __shared__ char smem[];
  float* s_rpe = (float*)(smem + O_RPE);
  const int tid = threadIdx.x;
  const int w   = blockIdx.x;
  const int wid = tid >> 6;
  const int lane = tid & 63;
  const int ql = lane & 15;
  const int lg = lane >> 4;
  const int h  = wid;
  const int ab = O_ATT + wid * ATT_STRIDE;

  {
    #pragma unroll
    for (int it = 0; it < 6; ++it) {
      int g = it * 512 + tid;
      int n = g >> 2, slot = g & 3;
      const char* src = (const char*)wTq + (size_t)n * 512 + ((slot * 16) ^ ((n & 3) << 4));
      gll16(src, smem + O_ATT + it * 8192 + wid * 1024);
    }
  }
  for (int f = tid; f < 1224; f += 512) s_rpe[f] = rpe_table[f];
  for (int f = tid; f < 400; f += 512) {
    float4 m4 = ((const float4*)(maskp + (size_t)w * 1600))[f];
    uint2 pk;
    pk.x = pk2(m4.x, m4.y); pk.y = pk2(m4.z, m4.w);
    *(uint2*)(smem + O_MSK + f * 8) = pk;
  }
  for (int p = tid; p < 1024; p += 512) {
    const int* rp = rel_pos + ((size_t)w * 1024 + p) * 3;
    int c0 = rp[0], c1 = rp[1], c2 = rp[2];
    c0 = min(25, max(-25, c0)); c1 = min(25, max(-25, c1)); c2 = min(25, max(-25, c2));
    unsigned pk = (unsigned)(c0 + 25) | ((unsigned)(c1 + 76) << 10) | ((unsigned)(c2 + 127) << 20);
    *(unsigned*)(smem + O_IDX + ((p * 4) ^ (((p >> 5) & 7) << 4))) = pk;
  }
  {
    const float4* src = (const float4*)(data + (size_t)w * 10240);
    for (int f = tid; f < 2560; f += 512) {
      int token = f >> 6, q4 = f & 63;
      float4 d4 = src[f];
      uint2 pk;
      pk.x = pk2(d4.x, d4.y); pk.y = pk2(d4.z, d4.w);
      *(uint2*)(smem + a_addr(token, q4 * 8)) = pk;
    }
    int token = 40 + (tid >> 6), byte = (tid & 63) * 8;
    *(uint2*)(smem + a_addr(token, byte)) = make_uint2(0u, 0u);
  }
  __syncthreads();

  f32x4 acc[18];
  #pragma unroll
  for (int i = 0; i < 18; ++i) acc[i] = (f32x4){0.f, 0.f, 0.f, 0.f};

  for (int t = 0; t < 8; ++t) {
    if (t < 7) {
      int bb = O_ATT + ((t + 1) & 1) * B1_SZ;
      #pragma unroll
      for (int it = 0; it < 6; ++it) {
        int g = it * 512 + tid;
        int n = g >> 2, slot = g & 3;
        const char* src = (const char*)wTq + (size_t)n * 512 + (t + 1) * 64
                          + ((slot * 16) ^ ((n & 3) << 4));
        gll16(src, smem + bb + it * 8192 + wid * 1024);
      }
    }
    const int bb = O_ATT + (t & 1) * B1_SZ;
    bf16x8 af[3];
    #pragma unroll
    for (int mt = 0; mt < 3; ++mt)
      af[mt] = ld16(smem + a_addr(mt * 16 + ql, t * 64 + lg * 16));
    #pragma unroll
    for (int j = 0; j < 6; ++j) {
      int n = ((j >> 1) * 16 + 2 * wid + (j & 1)) * 16 + ql;
      bf16x8 bf = ld16(smem + bb + n * 64 + ((lg * 16) ^ ((n & 3) << 4)));
      #pragma unroll
      for (int mt = 0; mt < 3; ++mt)
        acc[j * 3 + mt] = __builtin_amdgcn_mfma_f32_16x16x32_bf16(af[mt], bf, acc[j * 3 + mt], 0, 0, 0);
    }
    __syncthreads();
  }

  {
    #pragma unroll
    for (int it = 0; it < 4; ++it) {
      int g = it * 512 + tid;
      int n = g >> 3, slot = g & 7;
      const char* src = (const char*)pTq + (size_t)n * 512 + ((slot * 16) ^ ((n & 7) << 4));
      gll16(src, smem + B2_S + it * 8192 + wid * 1024);
    }
  }

  #pragma unroll
  for (int j = 0; j < 6; ++j) {
    int sec = j >> 1;
    int ncol = sec * 256 + 32 * wid + (j & 1) * 16 + ql;
    int d = (j & 1) * 16 + ql;
    float bias = qkv_b[ncol];
    float s1 = 0.f, s2 = 0.f;
    #pragma unroll
    for (int mt = 0; mt < 3; ++mt) {
      #pragma unroll
      for (int r = 0; r < 4; ++r) {
        int token = mt * 16 + lg * 4 + r;
        float v = acc[j * 3 + mt][r] + bias;
        if (token < 40) { s1 += v; s2 += v * v; }
        if (sec == 0)
          *(unsigned short*)(smem + ab + token * 80 + d * 2) = f2bf(v * SCALE_F);
        else if (sec == 1)
          *(unsigned short*)(smem + ab + AK + token * 80 + d * 2) = f2bf(v);
        else
          *(unsigned short*)(smem + ab + v_addr(d, token * 2)) = f2bf(v);
      }
    }
    s1 += __shfl_xor(s1, 16); s1 += __shfl_xor(s1, 32);
    s2 += __shfl_xor(s2, 16); s2 += __shfl_xor(s2, 32);
    if (lg == 0) { atomicAdd(ws + ncol, s1); atomicAdd(ws + 768 + ncol, s2); }
  }
  {
    int zd = lane >> 1;
    int zb = 96 + (lane & 1) * 16;
    *(int4*)(smem + ab + v_addr(zd, zb)) = (int4){0, 0, 0, 0};
  }
  asm volatile("" ::: "memory");

  f32x4 st[9];
  {
    bf16x8 kf[3], qf[3];
    #pragma unroll
    for (int a = 0; a < 3; ++a) kf[a] = ld16(smem + ab + AK + (a * 16 + ql) * 80 + lg * 16);
    #pragma unroll
    for (int b = 0; b < 3; ++b) qf[b] = ld16(smem + ab + (b * 16 + ql) * 80 + lg * 16);
    #pragma unroll
    for (int a = 0; a < 3; ++a)
      #pragma unroll
      for (int b = 0; b < 3; ++b)
        st[a * 3 + b] = __builtin_amdgcn_mfma_f32_16x16x32_bf16(
            kf[a], qf[b], (f32x4){0.f, 0.f, 0.f, 0.f}, 0, 0, 0);
  }

  float mx[3] = {-3e38f, -3e38f, -3e38f};
  #pragma unroll
  for (int a = 0; a < 3; ++a) {
    #pragma unroll
    for (int b = 0; b < 3; ++b) {
      #pragma unroll
      for (int r = 0; r < 4; ++r) {
        int kj = a * 16 + lg * 4 + r;
        int qi = b * 16 + ql;
        float s = st[a * 3 + b][r];
        if (kj < 40) {
          if (qi < 40) {
            s += bf2f(*(const unsigned short*)(smem + O_MSK + (qi * 40 + kj) * 2));
            if (kj >= 8 && qi >= 8) {
              int p = (qi - 8) * 32 + (kj - 8);
              unsigned pk = *(const unsigned*)(smem + O_IDX + ((p * 4) ^ (((p >> 5) & 7) << 4)));
              s += s_rpe[(pk & 1023) * 8 + h] + s_rpe[((pk >> 10) & 1023) * 8 + h]
                 + s_rpe[(pk >> 20) * 8 + h];
            }
          }
        } else {
          s = -1e30f;
        }
        st[a * 3 + b][r] = s;
        mx[b] = fmaxf(mx[b], s);
      }
    }
  }
  #pragma unroll
  for (int b = 0; b < 3; ++b) {
    mx[b] = fmaxf(mx[b], __shfl_xor(mx[b], 16));
    mx[b] = fmaxf(mx[b], __shfl_xor(mx[b], 32));
  }
  float sum[3] = {0.f, 0.f, 0.f};
  #pragma unroll
  for (int a = 0; a < 3; ++a)
    #pragma unroll
    for (int b = 0; b < 3; ++b)
      #pragma unroll
      for (int r = 0; r < 4; ++r) {
        float e = __expf(st[a * 3 + b][r] - mx[b]);
        st[a * 3 + b][r] = e;
        sum[b] += e;
      }
  float inv[3];
  #pragma unroll
  for (int b = 0; b < 3; ++b) {
    sum[b] += __shfl_xor(sum[b], 16);
    sum[b] += __shfl_xor(sum[b], 32);
    inv[b] = 1.f / sum[b];
  }

  f32x4 ot[6];
  #pragma unroll
  for (int i = 0; i < 6; ++i) ot[i] = (f32x4){0.f, 0.f, 0.f, 0.f};

  #pragma unroll
  for (int a = 0; a < 2; ++a)
    #pragma unroll
    for (int b = 0; b < 3; ++b)
      #pragma unroll
      for (int r = 0; r < 4; ++r) {
        int kj = a * 16 + lg * 4 + r, qi = b * 16 + ql;
        *(unsigned short*)(smem + ab + qi * 80 + kj * 2) = f2bf(st[a * 3 + b][r] * inv[b]);
      }
  asm volatile("" ::: "memory");
  {
    bf16x8 vf0 = ld16(smem + ab + v_addr(ql, lg * 16));
    bf16x8 vf1 = ld16(smem + ab + v_addr(16 + ql, lg * 16));
    #pragma unroll
    for (int b = 0; b < 3; ++b) {
      bf16x8 pf = ld16(smem + ab + (b * 16 + ql) * 80 + lg * 16);
      ot[b] = __builtin_amdgcn_mfma_f32_16x16x32_bf16(vf0, pf, ot[b], 0, 0, 0);
      ot[3 + b] = __builtin_amdgcn_mfma_f32_16x16x32_bf16(vf1, pf, ot[3 + b], 0, 0, 0);
    }
  }
  asm volatile("" ::: "memory");
  #pragma unroll
  for (int b = 0; b < 3; ++b) {
    int qi = b * 16 + ql;
    #pragma unroll
    for (int r = 0; r < 4; ++r) {
      int kj = 32 + lg * 4 + r;
      *(unsigned short*)(smem + ab + qi * 80 + (kj - 32) * 2) = f2bf(st[6 + b][r] * inv[b]);
    }
    *(uint2*)(smem + ab + qi * 80 + 32 + lg * 8) = make_uint2(0u, 0u);
  }
  asm volatile("" ::: "memory");
  {
    bf16x8 vf0 = ld16(smem + ab + v_addr(ql, 64 + lg * 16));
    bf16x8 vf1 = ld16(smem + ab + v_addr(16 + ql, 64 + lg * 16));
    #pragma unroll
    for (int b = 0; b < 3; ++b) {
      bf16x8 pf = ld16(smem + ab + (b * 16 + ql) * 80 + lg * 16);
      ot[b] = __builtin_amdgcn_mfma_f32_16x16x32_bf16(vf0, pf, ot[b], 0, 0, 0);
      ot[3 + b] = __builtin_amdgcn_mfma_f32_16x16x32_bf16(vf1, pf, ot[3 + b], 0, 0, 0);
    }
  }
  #pragma unroll
  for (int dm = 0; dm < 2; ++dm)
    #pragma unroll
    for (int b = 0; b < 3; ++b)
      #pragma unroll
      for (int r = 0; r < 4; ++r) {
        int d = dm * 16 + lg * 4 + r;
        int qi = b * 16 + ql;
        *(unsigned short*)(smem + a_addr(qi, (h * 32 + d) * 2)) = f2bf(ot[dm * 3 + b][r]);
      }
  __syncthreads();

  f32x4 oacc[6];
  #pragma unroll
  for (int i = 0; i < 6; ++i) oacc[i] = (f32x4){0.f, 0.f, 0.f, 0.f};

  for (int t = 0; t < 4; ++t) {
    if (t < 3) {
      int bb = ((t + 1) & 1) ? B2_A : B2_S;
      #pragma unroll
      for (int it = 0; it < 4; ++it) {
        int g = it * 512 + tid;
        int n = g >> 3, slot = g & 7;
        const char* src = (const char*)pTq + (size_t)n * 512 + (t + 1) * 128
                          + ((slot * 16) ^ ((n & 7) << 4));
        gll16(src, smem + bb + it * 8192 + wid * 1024);
      }
    }
    const int bb = (t & 1) ? B2_A : B2_S;
    #pragma unroll
    for (int ks = 0; ks < 2; ++ks) {
      bf16x8 af[3];
      #pragma unroll
      for (int mt = 0; mt < 3; ++mt)
        af[mt] = ld16(smem + a_addr(mt * 16 + ql, t * 128 + ks * 64 + lg * 16));
      #pragma unroll
      for (int nt = 0; nt < 2; ++nt) {
        int n = (2 * wid + nt) * 16 + ql;
        bf16x8 bf = ld16(smem + bb + n * 128 + ((ks * 64 + lg * 16) ^ ((n & 7) << 4)));
        #pragma unroll
        for (int mt = 0; mt < 3; ++mt)
          oacc[nt * 3 + mt] = __builtin_amdgcn_mfma_f32_16x16x32_bf16(af[mt], bf, oacc[nt * 3 + mt], 0, 0, 0);
      }
    }
    __syncthreads();
  }

  #pragma unroll
  for (int nt = 0; nt < 2; ++nt) {
    int ncol = (2 * wid + nt) * 16 + ql;
    float pb = proj_b[ncol];
    #pragma unroll
    for (int mt = 0; mt < 3; ++mt)
      #pragma unroll
      for (int r = 0; r < 4; ++r) {
        int token = mt * 16 + lg * 4 + r;
        if (token < 40)
          out[(size_t)w * 10240 + token * 256 + ncol] = oacc[nt * 3 + mt][r] + pb;
      }
  }
}

// =======================================================================
extern "C" void kernel_launch(void* const* d_in, const int* in_sizes, int n_in,
                              void* d_out, int out_size, void* d_ws, size_t ws_size,
                              hipStream_t stream) {
  const float* data    = (const float*)d_in[0];
  const int*   rel_pos = (const int*)d_in[1];
  const float* maskp   = (const float*)d_in[2];
  const float* qkv_w   = (const float*)d_in[3];
  const float* qkv_b   = (const float*)d_in[4];
  const float* proj_w  = (const float*)d_in[5];
  const float* proj_b  = (const float*)d_in[6];
  const float* rpe_tab = (const float*)d_in[7];
  float* out = (float*)d_out;
  float* ws  = (float*)d_ws;

  const int nw = in_sizes[1] / 3072;           // 4096
  const int total_rows = nw * 40;
  const size_t std_off = (size_t)nw * 10240;

  // ws layout (new path): [0,6144) sums | wTq 393216 | pTq 131072 | k/O 83886080
  const size_t WS_NEED = 530432ull + 83886080ull;

  unsigned short* wTq = (unsigned short*)((char*)d_ws + 6144);
  unsigned short* pTq = (unsigned short*)((char*)d_ws + 399360);

  hipMemsetAsync(ws, 0, 6144, stream);

  if (ws_size >= WS_NEED) {
    char* kg = (char*)d_ws + 530432;
    char* Og = kg;                               // O overwrites k (dead after attn reads)
    char* qg = (char*)d_out;                     // q in d_out[0, 83886080)
    char* vg = (char*)d_out + 83886080;          // vT in d_out[83886080, 167772160)

    hipLaunchKernelGGL(octa_prep2, dim3(1024), dim3(256), 0, stream, qkv_w, proj_w, wTq, pTq);
    hipLaunchKernelGGL(octa_qkv, dim3(nw * 40 / 64 * 2), dim3(512), K2_LDS, stream,
                       data, qkv_b, wTq, ws, qg, kg, vg);
    hipLaunchKernelGGL(octa_attn, dim3(nw), dim3(512), A2_LDS, stream,
                       qg, kg, vg, maskp, rel_pos, rpe_tab, Og);
    hipLaunchKernelGGL(octa_proj, dim3(nw * 40 / 128), dim3(512), P3_LDS, stream,
                       Og, pTq, proj_b, out);
    hipLaunchKernelGGL(octa_std, dim3(3), dim3(256), 0, stream, ws, out, total_rows, std_off);
  } else {
    hipLaunchKernelGGL(octa_prep_v4, dim3(1024), dim3(256), 0, stream, qkv_w, proj_w, wTq, pTq);
    (void)hipFuncSetAttribute((const void*)octa_main_v4,
                              hipFuncAttributeMaxDynamicSharedMemorySize, LDS_BYTES_V4);
    hipLaunchKernelGGL(octa_main_v4, dim3(nw), dim3(512), LDS_BYTES_V4, stream,
                       data, rel_pos, maskp, qkv_b, proj_b, rpe_tab, wTq, pTq, ws, out);
    hipLaunchKernelGGL(octa_std, dim3(3), dim3(256), 0, stream, ws, out, total_rows, std_off);
  }
}